// Round 1
// baseline (284.431 us; speedup 1.0000x reference)
//
#include <hip/hip_runtime.h>

// N1=4097, N2=8192. y = x[1:].reshape(8192, 4096); y[r,c] = x[r*4096 + c + 1]
// sum over r in [0,8191), c in [0,4095):
//   b[r,c] * (y[r,c] - prev^2)^2 ,  prev = y[r,c-1] (c>0) else y[r,4095]
// out = -a*(x[0]-mu)^2 - sum
//
// Layout: one block per row (8191 blocks x 256 threads). Thread t covers
// cols [16t, 16t+16): 4x float4 of x, 4x float4 of b, +1 scalar x[e+16].
// No loop, no loop-carried waits -> all 9 VMEM ops in flight at once.
// Boundary cases collapse to: t==0 (col-0 wrap) and t==255 (col-4095 mask).

#define ROWS  8191
#define BLOCK 256

__global__ __launch_bounds__(BLOCK) void rosen_partial(
    const float* __restrict__ x, const float* __restrict__ b,
    float* __restrict__ partial)
{
    const unsigned r = blockIdx.x;
    const unsigned t = threadIdx.x;
    const size_t   e = (size_t)r * 4096u + (size_t)t * 16u;

    const float4* __restrict__ x4 = (const float4*)(x + e);
    const float4* __restrict__ b4 = (const float4*)(b + e);

    // 9 independent loads, 128 B useful bytes/thread
    float4 xv0 = x4[0], xv1 = x4[1], xv2 = x4[2], xv3 = x4[3];
    float4 bv0 = b4[0], bv1 = b4[1], bv2 = b4[2], bv3 = b4[3];
    float  xs  = x[e + 16];

    float p0 = (t == 0) ? x[e + 4096] : xv0.x;  // col 0: prev wraps to y[r,4095]
    if (t == BLOCK - 1) bv3.w = 0.0f;           // col 4095: term excluded

    float d, acc;
    d = xv0.y - p0    * p0;     acc  = bv0.x * d * d;
    d = xv0.z - xv0.y * xv0.y;  acc += bv0.y * d * d;
    d = xv0.w - xv0.z * xv0.z;  acc += bv0.z * d * d;
    d = xv1.x - xv0.w * xv0.w;  acc += bv0.w * d * d;
    d = xv1.y - xv1.x * xv1.x;  acc += bv1.x * d * d;
    d = xv1.z - xv1.y * xv1.y;  acc += bv1.y * d * d;
    d = xv1.w - xv1.z * xv1.z;  acc += bv1.z * d * d;
    d = xv2.x - xv1.w * xv1.w;  acc += bv1.w * d * d;
    d = xv2.y - xv2.x * xv2.x;  acc += bv2.x * d * d;
    d = xv2.z - xv2.y * xv2.y;  acc += bv2.y * d * d;
    d = xv2.w - xv2.z * xv2.z;  acc += bv2.z * d * d;
    d = xv3.x - xv2.w * xv2.w;  acc += bv2.w * d * d;
    d = xv3.y - xv3.x * xv3.x;  acc += bv3.x * d * d;
    d = xv3.z - xv3.y * xv3.y;  acc += bv3.y * d * d;
    d = xv3.w - xv3.z * xv3.z;  acc += bv3.z * d * d;
    d = xs    - xv3.w * xv3.w;  acc += bv3.w * d * d;

    // wave-64 reduction
    #pragma unroll
    for (int off = 32; off > 0; off >>= 1)
        acc += __shfl_down(acc, off, 64);

    __shared__ float s[4];
    const int lane = t & 63;
    const int wid  = t >> 6;
    if (lane == 0) s[wid] = acc;
    __syncthreads();
    if (t == 0)
        partial[r] = s[0] + s[1] + s[2] + s[3];
}

__global__ __launch_bounds__(256) void rosen_final(const float* __restrict__ partial,
                                                   const float* __restrict__ x,
                                                   const float* __restrict__ a,
                                                   const float* __restrict__ mu,
                                                   float* __restrict__ out)
{
    float acc = 0.0f;
    for (int i = threadIdx.x; i < ROWS; i += 256)
        acc += partial[i];

    #pragma unroll
    for (int off = 32; off > 0; off >>= 1)
        acc += __shfl_down(acc, off, 64);

    __shared__ float s[4];
    const int lane = threadIdx.x & 63;
    const int wid  = threadIdx.x >> 6;
    if (lane == 0) s[wid] = acc;
    __syncthreads();
    if (threadIdx.x == 0) {
        float total = s[0] + s[1] + s[2] + s[3];
        float dd = x[0] - mu[0];
        out[0] = -a[0] * dd * dd - total;
    }
}

extern "C" void kernel_launch(void* const* d_in, const int* in_sizes, int n_in,
                              void* d_out, int out_size, void* d_ws, size_t ws_size,
                              hipStream_t stream) {
    const float* x  = (const float*)d_in[0];
    const float* a  = (const float*)d_in[1];
    const float* b  = (const float*)d_in[2];
    const float* mu = (const float*)d_in[3];
    float* out     = (float*)d_out;
    float* partial = (float*)d_ws;   // ROWS floats = 32.8 KB scratch

    rosen_partial<<<ROWS, BLOCK, 0, stream>>>(x, b, partial);
    rosen_final<<<1, 256, 0, stream>>>(partial, x, a, mu, out);
}

// Round 2
// 278.699 us; speedup vs baseline: 1.0206x; 1.0206x over previous
//
#include <hip/hip_runtime.h>

// N1=4097, N2=8192. y = x[1:].reshape(8192,4096); y[r,c] = x[r*4096+c+1]
// sum over r in [0,8191), c in [0,4095):
//   b[r,c] * (y[r,c] - prev^2)^2 ,  prev = y[r,c-1] (c>0) else y[r,4095]
// out = -a*(x[0]-mu)^2 - sum
//
// Round-2 shape: persistent grid (2048 blocks x 256 thr), each thread owns
// ITERS=4 independent 16-col groups. All 36 VMEM ops batched up front ->
// MLP from unrolled iterations, not workgroup churn (round-1 was dispatch-
// rate bound: 8191 one-shot blocks, ~11 KB/CU actually in flight).

#define ROWS     8191u
#define GROUPS16 (ROWS * 256u)              // 2,096,896 groups of 16 cols
#define GRID     2048
#define BLOCK    256
#define NTHREAD  ((unsigned)GRID * BLOCK)   // 524,288
#define ITERS    4                          // ceil(GROUPS16 / NTHREAD)

__device__ __forceinline__ float group16(const float4* xv, const float4* bv,
                                         float p0, float xs, float bw3)
{
    float d, s;
    d = xv[0].y - p0      * p0;       s  = bv[0].x * d * d;
    d = xv[0].z - xv[0].y * xv[0].y;  s += bv[0].y * d * d;
    d = xv[0].w - xv[0].z * xv[0].z;  s += bv[0].z * d * d;
    d = xv[1].x - xv[0].w * xv[0].w;  s += bv[0].w * d * d;
    d = xv[1].y - xv[1].x * xv[1].x;  s += bv[1].x * d * d;
    d = xv[1].z - xv[1].y * xv[1].y;  s += bv[1].y * d * d;
    d = xv[1].w - xv[1].z * xv[1].z;  s += bv[1].z * d * d;
    d = xv[2].x - xv[1].w * xv[1].w;  s += bv[1].w * d * d;
    d = xv[2].y - xv[2].x * xv[2].x;  s += bv[2].x * d * d;
    d = xv[2].z - xv[2].y * xv[2].y;  s += bv[2].y * d * d;
    d = xv[2].w - xv[2].z * xv[2].z;  s += bv[2].z * d * d;
    d = xv[3].x - xv[2].w * xv[2].w;  s += bv[2].w * d * d;
    d = xv[3].y - xv[3].x * xv[3].x;  s += bv[3].x * d * d;
    d = xv[3].z - xv[3].y * xv[3].y;  s += bv[3].y * d * d;
    d = xv[3].w - xv[3].z * xv[3].z;  s += bv[3].z * d * d;
    d = xs      - xv[3].w * xv[3].w;  s += bw3     * d * d;
    return s;
}

__global__ __launch_bounds__(BLOCK) void rosen_partial(
    const float* __restrict__ x, const float* __restrict__ b,
    float* __restrict__ partial)
{
    const unsigned tid = blockIdx.x * BLOCK + threadIdx.x;

    float4   xv[ITERS][4];
    float4   bv[ITERS][4];
    float    xs[ITERS];
    float    xw[ITERS];
    unsigned c16a[ITERS];
    bool     vld[ITERS];

    // ---- phase 1: issue ALL loads (independent, compile-time indexed) ----
    #pragma unroll
    for (int it = 0; it < ITERS; ++it) {
        unsigned g  = tid + (unsigned)it * NTHREAD;
        bool     v  = (g < GROUPS16);
        unsigned gc = v ? g : (GROUPS16 - 1u);   // clamp: harmless re-read
        unsigned c16 = gc & 255u;
        unsigned e   = (gc >> 8) * 4096u + c16 * 16u;
        vld[it]  = v;
        c16a[it] = c16;
        const float4* x4 = (const float4*)(x + e);
        const float4* b4 = (const float4*)(b + e);
        xv[it][0] = x4[0]; xv[it][1] = x4[1]; xv[it][2] = x4[2]; xv[it][3] = x4[3];
        bv[it][0] = b4[0]; bv[it][1] = b4[1]; bv[it][2] = b4[2]; bv[it][3] = b4[3];
        xs[it] = x[e + 16];
        float w = 0.0f;
        if (c16 == 0u) w = x[e + 4096];          // col-0 wrap: y[r,4095]
        xw[it] = w;
    }

    // ---- phase 2: compute ----
    float acc = 0.0f;
    #pragma unroll
    for (int it = 0; it < ITERS; ++it) {
        float p0  = (c16a[it] == 0u)   ? xw[it] : xv[it][0].x;
        float bw3 = (c16a[it] == 255u) ? 0.0f   : bv[it][3].w;  // col 4095 excluded
        float s = group16(&xv[it][0], &bv[it][0], p0, xs[it], bw3);
        acc += vld[it] ? s : 0.0f;
    }

    // ---- wave-64 + block reduction ----
    #pragma unroll
    for (int off = 32; off > 0; off >>= 1)
        acc += __shfl_down(acc, off, 64);

    __shared__ float sred[4];
    const int lane = threadIdx.x & 63;
    const int wid  = threadIdx.x >> 6;
    if (lane == 0) sred[wid] = acc;
    __syncthreads();
    if (threadIdx.x == 0)
        partial[blockIdx.x] = sred[0] + sred[1] + sred[2] + sred[3];
}

__global__ __launch_bounds__(256) void rosen_final(const float* __restrict__ partial,
                                                   const float* __restrict__ x,
                                                   const float* __restrict__ a,
                                                   const float* __restrict__ mu,
                                                   float* __restrict__ out)
{
    float acc = 0.0f;
    for (int i = threadIdx.x; i < GRID; i += 256)
        acc += partial[i];

    #pragma unroll
    for (int off = 32; off > 0; off >>= 1)
        acc += __shfl_down(acc, off, 64);

    __shared__ float sred[4];
    const int lane = threadIdx.x & 63;
    const int wid  = threadIdx.x >> 6;
    if (lane == 0) sred[wid] = acc;
    __syncthreads();
    if (threadIdx.x == 0) {
        float total = sred[0] + sred[1] + sred[2] + sred[3];
        float dd = x[0] - mu[0];
        out[0] = -a[0] * dd * dd - total;
    }
}

extern "C" void kernel_launch(void* const* d_in, const int* in_sizes, int n_in,
                              void* d_out, int out_size, void* d_ws, size_t ws_size,
                              hipStream_t stream) {
    const float* x  = (const float*)d_in[0];
    const float* a  = (const float*)d_in[1];
    const float* b  = (const float*)d_in[2];
    const float* mu = (const float*)d_in[3];
    float* out     = (float*)d_out;
    float* partial = (float*)d_ws;   // GRID floats = 8 KB scratch

    rosen_partial<<<GRID, BLOCK, 0, stream>>>(x, b, partial);
    rosen_final<<<1, 256, 0, stream>>>(partial, x, a, mu, out);
}